// Round 2
// 95.777 us; speedup vs baseline: 1.0983x; 1.0983x over previous
//
#include <hip/hip_runtime.h>
#include <hip/hip_fp16.h>

// SE3 divergence-free vector field — difference-profile table, v3.1.
//
// Only curl(psi) is needed and curl components are differences:
//   curl = (psi2-psi1, psi0-psi2, psi1-psi0) = (A, B, -A-B).
// So tabulate, per u (8 of them), the two scalar profiles
//   q0[u](r) = Psi[u][2]-Psi[u][1],  q1[u](r) = Psi[u][0]-Psi[u][2]
// with wcut(r)/(8*sqrt(8)) folded in.  Table: RTAB rows x 16 half2; entry
// t=2*u+q holds (q_t(r_i), q_t(r_{i+1})) -> ONE 64 B row gives both lerp
// endpoints.  Per edge: 2 accumulators, 2 HW float atomics (unsafeAtomicAdd
// -> global_atomic_add_f32, no CAS loop).  Copies-zeroing folded into the
// table-build kernel: 3 dispatches total.

#define THREADS 256
#define RTAB 2048
#define ROWH 32   // halves per row -> 64 B stride

__global__ __launch_bounds__(THREADS) void se3_build_table(
    const float* __restrict__ W1,   // (10, 64)
    const float* __restrict__ W2,   // (64, 384)
    __half* __restrict__ T,         // (RTAB, ROWH) halves
    float4* __restrict__ zbuf,      // copies region to zero
    int zcount4)
{
    __shared__ float sW1[10 * 65];
    __shared__ float sW2[64][25];   // 24 used cols of W2, padded

    for (int t = threadIdx.x; t < 640; t += THREADS) {
        int j = t >> 6, k = t & 63;
        sW1[j * 65 + k] = W1[t];
    }
    for (int t = threadIdx.x; t < 64 * 24; t += THREADS) {
        int k = t / 24, j = t - 24 * k;     // j = u*3 + c
        int u = j / 3, c = j - 3 * u;
        sW2[k][j] = W2[k * 384 + u * 32 + c];
    }

    int g = blockIdx.x * THREADS + threadIdx.x;

    // fold the copies-buffer memset into this kernel (independent of table)
    float4 z = make_float4(0.f, 0.f, 0.f, 0.f);
    for (int idx = g; idx < zcount4; idx += gridDim.x * THREADS)
        zbuf[idx] = z;

    __syncthreads();

    if (g >= RTAB * 8) return;
    int i = g >> 3;       // table row
    int u = g & 7;        // input feature

    float r = 3.0f * (float)i / (float)(RTAB - 1);
    float q0 = 0.f, q1 = 0.f;
    float t10 = 10.0f - (10.0f / 3.0f) * r;
    if (t10 > 0.0f) {
        // radial bump embedding: at most 2 of 10 basis functions non-zero.
        const float C0 = 8.43357306907549f;   // 1.14136*e^2 (sqrt10 cancels)
        float q  = r * (11.0f / 3.0f);
        int   jf = (int)q;
        float da = q - (float)jf;
        float db = da - 1.0f;
        float ya = fmaxf(1.0f - da * da, 1e-7f);
        float yb = fmaxf(1.0f - db * db, 1e-7f);
        int ja = jf - 1, jb = jf;
        float ea = (ja >= 0) ? C0 * __expf(-1.0f / ya) : 0.0f;
        float eb = (jb <= 9) ? C0 * __expf(-1.0f / yb) : 0.0f;
        int jac = ja < 0 ? 0 : ja;
        int jbc = jb > 9 ? 9 : jb;
        const float* w1a = sW1 + jac * 65;
        const float* w1b = sW1 + jbc * 65;

        float a0 = 0.f, a1 = 0.f, a2 = 0.f;
#pragma unroll 8
        for (int k = 0; k < 64; ++k) {
            float pre = ea * w1a[k] + eb * w1b[k];
            float h   = pre * __builtin_amdgcn_rcpf(1.0f + __expf(-pre)); // silu
            a0 = fmaf(h, sW2[k][u * 3 + 0], a0);
            a1 = fmaf(h, sW2[k][u * 3 + 1], a1);
            a2 = fmaf(h, sW2[k][u * 3 + 2], a2);
        }
        float sc = __expf(-1.0f / t10) * 0.04419417382415922f; // wcut/(8*sqrt8)
        q0 = (a2 - a1) * sc;   // psi2 - psi1 contribution
        q1 = (a0 - a2) * sc;   // psi0 - psi2 contribution
    }

    __half h0 = __float2half(q0);
    __half h1 = __float2half(q1);
    size_t base = (size_t)i * ROWH + 4 * u;
    T[base + 0] = h0;                       // row i, q0 .x endpoint
    T[base + 2] = h1;                       // row i, q1 .x endpoint
    if (i > 0) {
        T[base - ROWH + 1] = h0;            // row i-1, q0 .y endpoint
        T[base - ROWH + 3] = h1;            // row i-1, q1 .y endpoint
    }
    if (i == RTAB - 1) {                    // defensive: clear unused .y slots
        T[base + 1] = h0;
        T[base + 3] = h1;
    }
}

__global__ __launch_bounds__(THREADS) void se3_edge_kernel(
    const float* __restrict__ x,     // (B*N, 8)
    const float* __restrict__ pos,   // (B*N, 3)
    const int*   __restrict__ esrc,  // (E,)
    const int*   __restrict__ edst,  // (E,)
    const __half* __restrict__ T,    // (RTAB, ROWH)
    float*       __restrict__ outbuf,// ncopies x outN2, pre-zeroed
    int E, int ncopies, int outN2)
{
    int e = blockIdx.x * THREADS + threadIdx.x;
    if (e >= E) return;

    int s = esrc[e];
    int d = edst[e];

    float ex = pos[3 * s + 0] - pos[3 * d + 0];
    float ey = pos[3 * s + 1] - pos[3 * d + 1];
    float ez = pos[3 * s + 2] - pos[3 * d + 2];
    float r  = sqrtf(ex * ex + ey * ey + ez * ez + 1e-18f);

    if (r >= 3.0f) return;   // wcut == 0 -> edge contributes nothing

    float tq = r * ((float)(RTAB - 1) / 3.0f);
    int   i  = (int)tq;
    if (i > RTAB - 2) i = RTAB - 2;
    float f  = tq - (float)i;

    const float4* rowp = reinterpret_cast<const float4*>(T + (size_t)i * ROWH);
    const float4* xf   = reinterpret_cast<const float4*>(x + 8 * (size_t)s);
    float4 r0 = rowp[0], r1 = rowp[1], r2 = rowp[2], r3 = rowp[3];
    float4 xA = xf[0];
    float4 xB = xf[1];
    float x0 = xA.x, x1 = xA.y, x2 = xA.z, x3 = xA.w;
    float x4 = xB.x, x5 = xB.y, x6 = xB.z, x7 = xB.w;

    float c0 = 0.f, c1 = 0.f;
    // one float4 = entries for u2, u2+1: (q0,q1) each as half2(lo,hi)
    auto proc = [&](float4 v, float xu, float xv) {
        union { float4 f4; __half2 h[4]; } cv; cv.f4 = v;
        float2 a0 = __half22float2(cv.h[0]);
        float2 a1 = __half22float2(cv.h[1]);
        float2 a2 = __half22float2(cv.h[2]);
        float2 a3 = __half22float2(cv.h[3]);
        c0 = fmaf(xu, fmaf(f, a0.y - a0.x, a0.x), c0);
        c1 = fmaf(xu, fmaf(f, a1.y - a1.x, a1.x), c1);
        c0 = fmaf(xv, fmaf(f, a2.y - a2.x, a2.x), c0);
        c1 = fmaf(xv, fmaf(f, a3.y - a3.x, a3.x), c1);
    };
    proc(r0, x0, x1);
    proc(r1, x2, x3);
    proc(r2, x4, x5);
    proc(r3, x6, x7);

    // accumulate (A, B); third curl component reconstructed in reduce
    float* ob = outbuf + (size_t)(blockIdx.x % ncopies) * outN2 + 2 * d;
    unsafeAtomicAdd(ob + 0, c0);   // HW global_atomic_add_f32, no CAS loop
    unsafeAtomicAdd(ob + 1, c1);
}

__global__ __launch_bounds__(THREADS) void se3_reduce_kernel(
    const float* __restrict__ ws, float* __restrict__ out,
    int nNodes, int ncopies, int outN2)
{
    int n = blockIdx.x * THREADS + threadIdx.x;
    if (n >= nNodes) return;
    const float2* w = reinterpret_cast<const float2*>(ws);
    int stride2 = outN2 >> 1;
    float a = 0.f, b = 0.f;
    for (int c = 0; c < ncopies; ++c) {
        float2 v = w[(size_t)c * stride2 + n];
        a += v.x; b += v.y;
    }
    out[3 * n + 0] = a;
    out[3 * n + 1] = b;
    out[3 * n + 2] = -a - b;
}

extern "C" void kernel_launch(void* const* d_in, const int* in_sizes, int n_in,
                              void* d_out, int out_size, void* d_ws, size_t ws_size,
                              hipStream_t stream) {
    const float* x    = (const float*)d_in[0];
    const float* pos  = (const float*)d_in[1];
    const int*   esrc = (const int*)d_in[2];
    const int*   edst = (const int*)d_in[3];
    const float* W1   = (const float*)d_in[4];
    const float* W2   = (const float*)d_in[5];
    float* out = (float*)d_out;

    int E      = in_sizes[2];
    int outN   = out_size;        // B*N*3 floats
    int nNodes = outN / 3;
    int outN2  = 2 * nNodes;      // floats per accumulator copy

    size_t tableBytes = (size_t)RTAB * ROWH * sizeof(__half);  // 128 KB
    __half* T      = (__half*)d_ws;
    float*  copies = (float*)((char*)d_ws + tableBytes);

    size_t copyBytes = (size_t)outN2 * sizeof(float);
    int ncopies = 1;
    if (ws_size > tableBytes + copyBytes) {
        size_t rem = ws_size - tableBytes;
        int nc = (int)(rem / copyBytes);
        if (nc > 8) nc = 8;
        if (nc < 1) nc = 1;
        ncopies = nc;
    }
    int zcount4 = (int)(((size_t)ncopies * outN2) / 4);

    se3_build_table<<<(RTAB * 8) / THREADS, THREADS, 0, stream>>>(
        W1, W2, T, (float4*)copies, zcount4);

    se3_edge_kernel<<<(E + THREADS - 1) / THREADS, THREADS, 0, stream>>>(
        x, pos, esrc, edst, T, copies, E, ncopies, outN2);

    se3_reduce_kernel<<<(nNodes + THREADS - 1) / THREADS, THREADS, 0, stream>>>(
        copies, out, nNodes, ncopies, outN2);
}